// Round 15
// baseline (654.464 us; speedup 1.0000x reference)
//
#include <hip/hip_runtime.h>
#include <math.h>

#define B_   8
#define N_   8192
#define M_   2048
#define KNN  32
#define F1_  64
#define HID  32
#define DIV_ 4

typedef unsigned long long u64;
typedef unsigned int u32;

// ---------------------------------------------------------------------------
// P0: pack points -> float4{x,y,z,pn}, pn = fma(p2,p2,fma(p1,p1,p0*p0))
// ---------------------------------------------------------------------------
__global__ __launch_bounds__(256) void pack_kernel(
    const float* __restrict__ points, float4* __restrict__ ppk)
{
  const int i = blockIdx.x*256 + threadIdx.x;        // 0..65535
  const float* pp = &points[(size_t)i*3];
  float px = pp[0], py = pp[1], pz = pp[2];
  float pn = __builtin_fmaf(pz, pz, __builtin_fmaf(py, py, __fmul_rn(px, px)));
  ppk[i] = make_float4(px, py, pz, pn);
}

// ---------------------------------------------------------------------------
// K1: exact KNN (x-first FMA chain — VERIFIED bit-matching r4; do not change)
//   dot = fma(q2,p2, fma(q1,p1, q0*p0));  d2 = fma(-2, dot, qn+pn)
// r15: amdgpu_waves_per_eu(4,4) — sets the allocator's occupancy TARGET
// (launch_bounds min-waves only caps; r14 showed the heuristic still
// squeezed to VGPR=32, spilling the u64 cache into AGPR moves ->
// ~3.5x instruction inflation, VALU-busy 193us vs ~55us ideal).
// ---------------------------------------------------------------------------
__device__ __forceinline__ u32 ord_f32(float f) {
  u32 u = __float_as_uint(f);
  return u ^ (u32)(((int)u >> 31) | 0x80000000);
}

#define KNN_INSERT(PV, NV)                                                    \
  {                                                                           \
    const int n_ = (NV);                                                      \
    _Pragma("unroll")                                                         \
    for (int q = 0; q < 2; ++q) {                                             \
      float dot = __builtin_fmaf(qz[q], (PV).z,                               \
                  __builtin_fmaf(qy[q], (PV).y, __fmul_rn(qx[q], (PV).x)));   \
      float s_  = __fadd_rn(qn[q], (PV).w);                                   \
      float d2  = __builtin_fmaf(-2.0f, dot, s_);                             \
      u64 key = ((u64)ord_f32(d2) << 32) | (u32)n_;                           \
      u64 a0 = key < c0[q] ? key   : c0[q];                                   \
      u64 A0 = key < c0[q] ? c0[q] : key;                                     \
      u64 a1 = A0 < c1[q] ? A0    : c1[q];                                    \
      u64 A1 = A0 < c1[q] ? c1[q] : A0;                                      \
      u64 a2 = A1 < c2[q] ? A1    : c2[q];                                   \
      c0[q] = a0; c1[q] = a1; c2[q] = a2;                                    \
    }                                                                         \
  }

__attribute__((amdgpu_waves_per_eu(4, 4)))
__global__ __launch_bounds__(256) void knn_kernel(
    const float4* __restrict__ ppk, const float* __restrict__ queries,
    int* __restrict__ idx_out, float* __restrict__ local_out)
{
  const int bid = blockIdx.x;            // 0..2047
  const int b = bid >> 8;                // 256 blocks per batch
  const int qbase = (bid & 255) * 8;     // 8 queries per block
  const int t = threadIdx.x, lane = t & 63, wid = t >> 6;

  const int q0 = qbase + wid*2;          // 2 queries per wave
  float qx[2], qy[2], qz[2], qn[2];
  u64 c0[2], c1[2], c2[2];
  #pragma unroll
  for (int q = 0; q < 2; ++q) {
    int m = q0 + q;
    qx[q] = queries[(b*M_+m)*3+0];
    qy[q] = queries[(b*M_+m)*3+1];
    qz[q] = queries[(b*M_+m)*3+2];
    qn[q] = __builtin_fmaf(qz[q], qz[q], __builtin_fmaf(qy[q], qy[q], __fmul_rn(qx[q], qx[q])));
    c0[q] = c1[q] = c2[q] = ~0ull;
  }

  const float4* __restrict__ base = ppk + (size_t)b * N_;

  // scan all 8192 points; per-lane top-3 cache; depth-2 prefetch, peeled tail
  float4 pa = base[lane];
  float4 pb = base[64 + lane];
  #pragma unroll 2
  for (int j = 0; j < 126; ++j) {
    const float4 pc = base[(j+2)*64 + lane];
    KNN_INSERT(pa, j*64 + lane);
    pa = pb; pb = pc;
  }
  KNN_INSERT(pa, 126*64 + lane);
  KNN_INSERT(pb, 127*64 + lane);

  // extraction: dual-query interleaved wave-wide min-extraction
  u64 e0[2] = {c0[0], c0[1]}, e1[2] = {c1[0], c1[1]}, e2[2] = {c2[0], c2[1]};
  u64 cand[2] = {e0[0], e0[1]};
  u64 mykey[2] = {~0ull, ~0ull};
  int rem[2] = {3, 3};

  for (int r = 0; r < KNN; ++r) {
    u64 wa = cand[0], wb = cand[1];
    #pragma unroll
    for (int dlt = 1; dlt < 64; dlt <<= 1) {
      u64 oa = __shfl_xor(wa, dlt);
      u64 ob = __shfl_xor(wb, dlt);
      wa = oa < wa ? oa : wa;
      wb = ob < wb ? ob : wb;
    }
    if (lane == r) { mykey[0] = wa; mykey[1] = wb; }
    u64 w2q[2] = {wa, wb};
    #pragma unroll
    for (int q = 0; q < 2; ++q) {
      const u64 w = w2q[q];
      if (cand[q] == w) {              // this lane supplied the winner
        e0[q] = e1[q]; e1[q] = e2[q]; e2[q] = ~0ull; --rem[q];
        if (rem[q] == 0) {
          // rare: rebuild top-3 of this lane's keys strictly greater than w
          const u64 lim = w;
          u64 f0 = ~0ull, f1 = ~0ull, f2 = ~0ull;
          for (int j = 0; j < 128; ++j) {
            int n = j*64 + lane;
            const float4 p = base[n];
            float dot = __builtin_fmaf(qz[q], p.z, __builtin_fmaf(qy[q], p.y, __fmul_rn(qx[q], p.x)));
            float d2  = __builtin_fmaf(-2.0f, dot, __fadd_rn(qn[q], p.w));
            u64 key = ((u64)ord_f32(d2) << 32) | (u32)n;
            if (key > lim) {
              u64 a0 = key < f0 ? key : f0;
              u64 A0 = key < f0 ? f0  : key;
              u64 a1 = A0 < f1 ? A0   : f1;
              u64 A1 = A0 < f1 ? f1   : A0;
              u64 a2 = A1 < f2 ? A1   : f2;
              f0 = a0; f1 = a1; f2 = a2;
            }
          }
          e0[q] = f0; e1[q] = f1; e2[q] = f2;
          rem[q] = (f2 != ~0ull) ? 3 : ((f1 != ~0ull) ? 2 : ((f0 != ~0ull) ? 1 : 0));
        }
        cand[q] = e0[q];
      }
    }
  }

  #pragma unroll
  for (int q = 0; q < 2; ++q) {
    if (lane < KNN) {
      u32 n = (u32)mykey[q];
      int bm = b*M_ + q0 + q;
      idx_out[bm*KNN + lane] = (int)n;
      const float4 p = base[n];
      local_out[(bm*KNN + lane)*3 + 0] = qx[q] - p.x;
      local_out[(bm*KNN + lane)*3 + 1] = qy[q] - p.y;
      local_out[(bm*KNN + lane)*3 + 2] = qz[q] - p.z;
    }
  }
}

// ---------------------------------------------------------------------------
// BN1 stats over local (B*M*K rows x 3 ch) — 1024 blocks (was 256)
// ---------------------------------------------------------------------------
__global__ __launch_bounds__(256) void bn1_stats_kernel(
    const float* __restrict__ local, float* __restrict__ p1)
{
  const int t = threadIdx.x;
  const int gid = blockIdx.x*256 + t;
  float s0=0,s1=0,s2=0,q0=0,q1=0,q2=0;
  for (int r = gid; r < B_*M_*KNN; r += 262144) {
    float a = local[r*3+0], b = local[r*3+1], c = local[r*3+2];
    s0 += a; s1 += b; s2 += c;
    q0 = fmaf(a,a,q0); q1 = fmaf(b,b,q1); q2 = fmaf(c,c,q2);
  }
  __shared__ float red[256][8];
  red[t][0]=s0; red[t][1]=s1; red[t][2]=s2; red[t][3]=0.f;
  red[t][4]=q0; red[t][5]=q1; red[t][6]=q2; red[t][7]=0.f;
  __syncthreads();
  for (int st = 128; st >= 1; st >>= 1) {
    if (t < st) {
      #pragma unroll
      for (int j = 0; j < 8; ++j) red[t][j] += red[t+st][j];
    }
    __syncthreads();
  }
  if (t < 8) p1[blockIdx.x*8 + t] = red[0][t];
}

__global__ __launch_bounds__(128) void bn1_fold_kernel(
    const float* __restrict__ p1, const float* __restrict__ g1, const float* __restrict__ be1,
    const float* __restrict__ w1, const float* __restrict__ b1, float* __restrict__ prm)
{
  __shared__ float sc[3], sh[3];
  const int t = threadIdx.x;
  if (t < 3) {
    double s = 0, q = 0;
    for (int blk = 0; blk < 1024; ++blk) { s += p1[blk*8+t]; q += p1[blk*8+4+t]; }
    double n = (double)(B_*M_*KNN);
    double m = s/n, v = q/n - m*m;
    double rs = 1.0/sqrt(v + 1e-5);
    float scale = (float)((double)g1[t]*rs);
    sc[t] = scale; sh[t] = be1[t] - (float)m*scale;
  }
  __syncthreads();
  if (t < 96) prm[t] = w1[t]*sc[t/32];
  if (t < 32) {
    float a = b1[t];
    for (int c = 0; c < 3; ++c) a = fmaf(sh[c], w1[c*32+t], a);
    prm[96+t] = a;
  }
}

// ---------------------------------------------------------------------------
// h1 stats (recomputes h1 = relu(local @ w1f + b1f)), 32 ch — 1024 blocks
// ---------------------------------------------------------------------------
__global__ __launch_bounds__(256) void h1_stats_kernel(
    const float* __restrict__ local, const float* __restrict__ prm, float* __restrict__ p2)
{
  const int t = threadIdx.x;
  const int k4 = (t & 7) * 4;
  float w0[4], w1q[4], w2q[4], b1q[4];
  #pragma unroll
  for (int i = 0; i < 4; ++i) {
    w0[i]  = prm[ 0 + k4 + i];
    w1q[i] = prm[32 + k4 + i];
    w2q[i] = prm[64 + k4 + i];
    b1q[i] = prm[96 + k4 + i];
  }
  float s[4] = {0,0,0,0}, sq[4] = {0,0,0,0};
  const int r0 = (blockIdx.x*256 + t) >> 3;
  for (int r = r0; r < B_*M_*KNN; r += 32768) {
    float l0 = local[r*3+0], l1 = local[r*3+1], l2 = local[r*3+2];
    #pragma unroll
    for (int i = 0; i < 4; ++i) {
      float v = fmaf(l2, w2q[i], fmaf(l1, w1q[i], fmaf(l0, w0[i], b1q[i])));
      v = fmaxf(v, 0.0f);
      s[i] += v; sq[i] = fmaf(v, v, sq[i]);
    }
  }
  __shared__ float red[256][8];
  #pragma unroll
  for (int i = 0; i < 4; ++i) { red[t][i] = s[i]; red[t][4+i] = sq[i]; }
  __syncthreads();
  for (int st = 128; st >= 8; st >>= 1) {
    if (t < st) {
      #pragma unroll
      for (int j = 0; j < 8; ++j) red[t][j] += red[t+st][j];
    }
    __syncthreads();
  }
  if (t < 8) {
    #pragma unroll
    for (int i = 0; i < 4; ++i) {
      p2[blockIdx.x*64 +      t*4 + i] = red[t][i];
      p2[blockIdx.x*64 + 32 + t*4 + i] = red[t][4+i];
    }
  }
}

__global__ __launch_bounds__(64) void bn2_fold_kernel(
    const float* __restrict__ p2, const float* __restrict__ g2, const float* __restrict__ be2,
    const float* __restrict__ w2, const float* __restrict__ b2, float* __restrict__ prm)
{
  __shared__ float sc[32], sh[32];
  const int t = threadIdx.x;
  if (t < 32) {
    double s = 0, q = 0;
    for (int blk = 0; blk < 1024; ++blk) { s += p2[blk*64+t]; q += p2[blk*64+32+t]; }
    double n = (double)(B_*M_*KNN);
    double m = s/n, v = q/n - m*m;
    double rs = 1.0/sqrt(v + 1e-5);
    float scale = (float)((double)g2[t]*rs);
    sc[t] = scale; sh[t] = be2[t] - (float)m*scale;
  }
  __syncthreads();
  {
    int j = t;
    float a = b2[j];
    for (int k = 0; k < 32; ++k) {
      float wv = w2[k*64 + j];
      prm[128 + j*32 + k] = wv * sc[k];
      a = fmaf(sh[k], wv, a);
    }
    prm[2176 + j] = a;
  }
}

// ---------------------------------------------------------------------------
// fused: h2 = relu(h1 @ w2ft + b2f) + maxpool(8) -> pooled[.,0:64]
//        AND feat_prev gather + maxpool(8)       -> pooled[.,64:128]
// ---------------------------------------------------------------------------
__global__ __launch_bounds__(256) void h2_prev_pool_kernel(
    const float* __restrict__ local, const float* __restrict__ prm,
    const float* __restrict__ feat_prev, const int* __restrict__ idx,
    float* __restrict__ pooled)
{
  const int t = threadIdx.x;
  const int row = blockIdx.x*256 + t;
  const int bm = row >> 5, s = row & 31, d = s >> 3;
  const float l0 = local[row*3+0], l1 = local[row*3+1], l2 = local[row*3+2];
  float h1v[32];
  #pragma unroll
  for (int k = 0; k < 32; ++k) {
    float v = fmaf(l2, prm[64+k], fmaf(l1, prm[32+k], fmaf(l0, prm[0+k], prm[96+k])));
    h1v[k] = fmaxf(v, 0.0f);
  }
  const float* __restrict__ w2t = prm + 128;
  const float* __restrict__ b2f = prm + 2176;
  #pragma unroll 4
  for (int j = 0; j < 64; ++j) {
    float acc = b2f[j];
    #pragma unroll
    for (int k = 0; k < 32; ++k) acc = fmaf(h1v[k], w2t[j*32+k], acc);
    acc = fmaxf(acc, 0.0f);
    acc = fmaxf(acc, __shfl_xor(acc, 1));
    acc = fmaxf(acc, __shfl_xor(acc, 2));
    acc = fmaxf(acc, __shfl_xor(acc, 4));
    if ((s & 7) == 0) pooled[(bm*4 + d)*128 + j] = acc;
  }
  const int bm0 = blockIdx.x * 8;
  #pragma unroll
  for (int it = 0; it < 8; ++it) {
    const int task = it*256 + t;
    const int bmL  = task >> 8;
    const int dd   = (task >> 6) & 3;
    const int ch   = task & 63;
    const int bmg  = bm0 + bmL;
    const int bb   = bmg >> 11;
    float pm = -3.402823466e+38f;
    #pragma unroll
    for (int s8 = 0; s8 < 8; ++s8) {
      int n = idx[bmg*KNN + dd*8 + s8];
      float v = feat_prev[((size_t)(bb*N_ + n))*64 + ch];
      pm = fmaxf(pm, v);
    }
    pooled[(size_t)(bmg*4 + dd)*128 + 64 + ch] = pm;
  }
}

// ---------------------------------------------------------------------------
// BN3 stats over pooled (B*M*4 rows x 128 ch) — 512 blocks
// ---------------------------------------------------------------------------
__global__ __launch_bounds__(256) void bn3_stats_kernel(
    const float* __restrict__ pooled, float* __restrict__ p3)
{
  const int t = threadIdx.x, c = t & 127, rr = t >> 7;
  float s = 0, q = 0;
  for (int r = blockIdx.x*2 + rr; r < B_*M_*DIV_; r += 1024) {
    float v = pooled[(size_t)r*128 + c];
    s += v; q = fmaf(v, v, q);
  }
  __shared__ float red[256][2];
  red[t][0] = s; red[t][1] = q;
  __syncthreads();
  if (t < 128) {
    p3[blockIdx.x*256 +       t] = red[t][0] + red[t+128][0];
    p3[blockIdx.x*256 + 128 + t] = red[t][1] + red[t+128][1];
  }
}

// 1024 threads: the 64K-element weight transform was the serial cost at 256
__global__ __launch_bounds__(1024) void bn3_fold_kernel(
    const float* __restrict__ p3, const float* __restrict__ g3, const float* __restrict__ be3,
    const float* __restrict__ wc, const float* __restrict__ bc, float* __restrict__ prm)
{
  __shared__ float sc[128], sh[128];
  const int t = threadIdx.x;
  if (t < 128) {
    double s = 0, q = 0;
    for (int blk = 0; blk < 512; ++blk) { s += p3[blk*256+t]; q += p3[blk*256+128+t]; }
    double n = (double)(B_*M_*DIV_);
    double m = s/n, v = q/n - m*m;
    double rs = 1.0/sqrt(v + 1e-5);
    float scale = (float)((double)g3[t]*rs);
    sc[t] = scale; sh[t] = be3[t] - (float)m*scale;
  }
  __syncthreads();
  for (int e = t; e < 512*128; e += 1024) {
    int i = e >> 7, o = e & 127, dd = i >> 7, cc = i & 127;
    prm[2240 + e] = wc[o*512 + cc*4 + dd] * sc[cc];
  }
  if (t < 128) {
    int o = t;
    float a = bc[o];
    for (int cc = 0; cc < 128; ++cc) {
      float hsum = 0;
      #pragma unroll
      for (int dd = 0; dd < 4; ++dd) hsum += wc[o*512 + cc*4 + dd];
      a = fmaf(sh[cc], hsum, a);
    }
    prm[67776 + o] = a;
  }
}

// ---------------------------------------------------------------------------
// out = relu(pooled(16384x512) @ wcf_t(512x128) + bcf) ; fp32 tiled GEMM
// tile 32x128, 512 blocks, thread tile 2x8
// ---------------------------------------------------------------------------
__global__ __launch_bounds__(256) void conv_gemm_kernel(
    const float* __restrict__ pooled, const float* __restrict__ prm,
    float* __restrict__ outp)
{
  const float* __restrict__ Bw  = prm + 2240;    // [512][128]
  const float* __restrict__ bcf = prm + 67776;   // [128]
  __shared__ float As[32][36];
  __shared__ float Bs[32][128];
  const int t = threadIdx.x;
  const int cg_ = t & 15, rg = t >> 4;
  const int rowbase = blockIdx.x * 32;
  float acc[2][8];
  #pragma unroll
  for (int i = 0; i < 2; ++i)
    #pragma unroll
    for (int j = 0; j < 8; ++j) acc[i][j] = 0.f;

  float bb[8];
  #pragma unroll
  for (int j = 0; j < 8; ++j) bb[j] = bcf[cg_*8 + j];

  for (int k0 = 0; k0 < 512; k0 += 32) {
    {
      int r = t >> 3, qd = t & 7;
      const float4 v = *(const float4*)&pooled[(size_t)(rowbase+r)*512 + k0 + qd*4];
      As[qd*4+0][r] = v.x; As[qd*4+1][r] = v.y; As[qd*4+2][r] = v.z; As[qd*4+3][r] = v.w;
    }
    #pragma unroll
    for (int i = 0; i < 4; ++i) {
      int li = t + i*256;
      int kk = li >> 5, c4 = (li & 31) * 4;
      *(float4*)&Bs[kk][c4] = *(const float4*)&Bw[(size_t)(k0+kk)*128 + c4];
    }
    __syncthreads();
    #pragma unroll 8
    for (int kk = 0; kk < 32; ++kk) {
      float a0 = As[kk][rg*2], a1 = As[kk][rg*2+1];
      float4 b0 = *(const float4*)&Bs[kk][cg_*8];
      float4 b1 = *(const float4*)&Bs[kk][cg_*8+4];
      float bv[8] = {b0.x, b0.y, b0.z, b0.w, b1.x, b1.y, b1.z, b1.w};
      #pragma unroll
      for (int j = 0; j < 8; ++j) {
        acc[0][j] = fmaf(a0, bv[j], acc[0][j]);
        acc[1][j] = fmaf(a1, bv[j], acc[1][j]);
      }
    }
    __syncthreads();
  }
  #pragma unroll
  for (int i = 0; i < 2; ++i) {
    int r = rowbase + rg*2 + i;
    float4 o0, o1;
    o0.x = fmaxf(acc[i][0] + bb[0], 0.f);
    o0.y = fmaxf(acc[i][1] + bb[1], 0.f);
    o0.z = fmaxf(acc[i][2] + bb[2], 0.f);
    o0.w = fmaxf(acc[i][3] + bb[3], 0.f);
    o1.x = fmaxf(acc[i][4] + bb[4], 0.f);
    o1.y = fmaxf(acc[i][5] + bb[5], 0.f);
    o1.z = fmaxf(acc[i][6] + bb[6], 0.f);
    o1.w = fmaxf(acc[i][7] + bb[7], 0.f);
    *(float4*)&outp[(size_t)r*128 + cg_*8    ] = o0;
    *(float4*)&outp[(size_t)r*128 + cg_*8 + 4] = o1;
  }
}

// ---------------------------------------------------------------------------
extern "C" void kernel_launch(void* const* d_in, const int* in_sizes, int n_in,
                              void* d_out, int out_size, void* d_ws, size_t ws_size,
                              hipStream_t stream)
{
  (void)in_sizes; (void)n_in; (void)out_size; (void)ws_size;
  const float* points    = (const float*)d_in[0];
  const float* queries   = (const float*)d_in[1];
  const float* feat_prev = (const float*)d_in[2];
  const float* w1  = (const float*)d_in[3];
  const float* b1  = (const float*)d_in[4];
  const float* w2  = (const float*)d_in[5];
  const float* b2  = (const float*)d_in[6];
  const float* g1  = (const float*)d_in[7];
  const float* be1 = (const float*)d_in[8];
  const float* g2  = (const float*)d_in[9];
  const float* be2 = (const float*)d_in[10];
  const float* g3  = (const float*)d_in[11];
  const float* be3 = (const float*)d_in[12];
  const float* wc  = (const float*)d_in[13];
  const float* bc  = (const float*)d_in[14];
  float* outp = (float*)d_out;

  char* ws = (char*)d_ws;
  int*   idx    = (int*)ws;                          // 2MB
  float* local  = (float*)(ws + (2u<<20));           // 6MB  -> ends 8MB
  float* pooled = (float*)(ws + (8u<<20));           // 32MB -> ends 40MB
  float* prm    = (float*)(ws + (40u<<20));          // ~275KB
  float* p1     = (float*)(ws + (41u<<20));          // 8192 f (32KB)
  float* p2     = p1 + 8192;                         // 65536 f (256KB)
  float4* ppk   = (float4*)(ws + (42u<<20));         // 1MB
  float* p3     = (float*)(ws + (43u<<20));          // 131072 f (512KB)

  pack_kernel    <<<256,   256, 0, stream>>>(points, ppk);
  knn_kernel     <<<2048,  256, 0, stream>>>(ppk, queries, idx, local);
  bn1_stats_kernel<<<1024, 256, 0, stream>>>(local, p1);
  bn1_fold_kernel<<<1,     128, 0, stream>>>(p1, g1, be1, w1, b1, prm);
  h1_stats_kernel<<<1024,  256, 0, stream>>>(local, prm, p2);
  bn2_fold_kernel<<<1,      64, 0, stream>>>(p2, g2, be2, w2, b2, prm);
  h2_prev_pool_kernel<<<2048, 256, 0, stream>>>(local, prm, feat_prev, idx, pooled);
  bn3_stats_kernel<<<512,  256, 0, stream>>>(pooled, p3);
  bn3_fold_kernel<<<1,    1024, 0, stream>>>(p3, g3, be3, wc, bc, prm);
  conv_gemm_kernel<<<512,  256, 0, stream>>>(pooled, prm, outp);
}

// Round 16
// 559.974 us; speedup vs baseline: 1.1687x; 1.1687x over previous
//
#include <hip/hip_runtime.h>
#include <math.h>

#define B_   8
#define N_   8192
#define M_   2048
#define KNN  32
#define F1_  64
#define HID  32
#define DIV_ 4

typedef unsigned long long u64;
typedef unsigned int u32;

// ---------------------------------------------------------------------------
// P0: pack points -> float4{x,y,z,pn}, pn = fma(p2,p2,fma(p1,p1,p0*p0))
// ---------------------------------------------------------------------------
__global__ __launch_bounds__(256) void pack_kernel(
    const float* __restrict__ points, float4* __restrict__ ppk)
{
  const int i = blockIdx.x*256 + threadIdx.x;        // 0..65535
  const float* pp = &points[(size_t)i*3];
  float px = pp[0], py = pp[1], pz = pp[2];
  float pn = __builtin_fmaf(pz, pz, __builtin_fmaf(py, py, __fmul_rn(px, px)));
  ppk[i] = make_float4(px, py, pz, pn);
}

// ---------------------------------------------------------------------------
// K1: exact KNN (x-first FMA chain — VERIFIED bit-matching r4; do not change)
//   dot = fma(q2,p2, fma(q1,p1, q0*p0));  d2 = fma(-2, dot, qn+pn)
// r16: scan insert = (f32 d2, u32 idx) with 3 PARALLEL compares (lt0,lt1,lt2)
// — replaces the 5-deep serial u64 min/max chain (r14/r15 showed identical
// 193us VALU-busy time at VGPR 32 and 52: cost is the op count + serial
// deps, not registers). Strict < keeps incumbent => tie->lower-index, since
// per-lane scan is in increasing n. Extraction identical to r14 (u64 keys
// packed from (c,i) after the scan; rescan path unchanged).
// ---------------------------------------------------------------------------
__device__ __forceinline__ u32 ord_f32(float f) {
  u32 u = __float_as_uint(f);
  return u ^ (u32)(((int)u >> 31) | 0x80000000);
}

#define KNN_INSERT(PV, NV)                                                    \
  {                                                                           \
    const u32 n_ = (NV);                                                      \
    _Pragma("unroll")                                                         \
    for (int q = 0; q < 2; ++q) {                                             \
      float dot = __builtin_fmaf(qz[q], (PV).z,                               \
                  __builtin_fmaf(qy[q], (PV).y, __fmul_rn(qx[q], (PV).x)));   \
      float s_  = __fadd_rn(qn[q], (PV).w);                                   \
      float d2  = __builtin_fmaf(-2.0f, dot, s_);                             \
      const bool lt0 = d2 < c0[q];                                            \
      const bool lt1 = d2 < c1[q];                                            \
      const bool lt2 = d2 < c2[q];                                            \
      c2[q] = lt1 ? c1[q] : (lt2 ? d2 : c2[q]);                               \
      i2[q] = lt1 ? i1[q] : (lt2 ? n_ : i2[q]);                               \
      c1[q] = lt0 ? c0[q] : (lt1 ? d2 : c1[q]);                               \
      i1[q] = lt0 ? i0[q] : (lt1 ? n_ : i1[q]);                               \
      c0[q] = lt0 ? d2 : c0[q];                                               \
      i0[q] = lt0 ? n_ : i0[q];                                               \
    }                                                                         \
  }

__global__ __launch_bounds__(256, 6) void knn_kernel(
    const float4* __restrict__ ppk, const float* __restrict__ queries,
    int* __restrict__ idx_out, float* __restrict__ local_out)
{
  const int bid = blockIdx.x;            // 0..2047
  const int b = bid >> 8;                // 256 blocks per batch
  const int qbase = (bid & 255) * 8;     // 8 queries per block
  const int t = threadIdx.x, lane = t & 63, wid = t >> 6;

  const int q0 = qbase + wid*2;          // 2 queries per wave
  float qx[2], qy[2], qz[2], qn[2];
  float c0[2], c1[2], c2[2];
  u32 i0[2], i1[2], i2[2];
  #pragma unroll
  for (int q = 0; q < 2; ++q) {
    int m = q0 + q;
    qx[q] = queries[(b*M_+m)*3+0];
    qy[q] = queries[(b*M_+m)*3+1];
    qz[q] = queries[(b*M_+m)*3+2];
    qn[q] = __builtin_fmaf(qz[q], qz[q], __builtin_fmaf(qy[q], qy[q], __fmul_rn(qx[q], qx[q])));
    c0[q] = c1[q] = c2[q] = __builtin_inff();
    i0[q] = i1[q] = i2[q] = 0u;
  }

  const float4* __restrict__ base = ppk + (size_t)b * N_;

  // scan all 8192 points; per-lane top-3 cache; depth-2 prefetch, peeled tail
  float4 pa = base[lane];
  float4 pb = base[64 + lane];
  #pragma unroll 2
  for (int j = 0; j < 126; ++j) {
    const float4 pc = base[(j+2)*64 + lane];
    KNN_INSERT(pa, j*64 + lane);
    pa = pb; pb = pc;
  }
  KNN_INSERT(pa, 126*64 + lane);
  KNN_INSERT(pb, 127*64 + lane);

  // pack (c,i) -> u64 keys; extraction identical to r14
  u64 e0[2], e1[2], e2[2];
  #pragma unroll
  for (int q = 0; q < 2; ++q) {
    e0[q] = ((u64)ord_f32(c0[q]) << 32) | i0[q];
    e1[q] = ((u64)ord_f32(c1[q]) << 32) | i1[q];
    e2[q] = ((u64)ord_f32(c2[q]) << 32) | i2[q];
  }
  u64 cand[2] = {e0[0], e0[1]};
  u64 mykey[2] = {~0ull, ~0ull};
  int rem[2] = {3, 3};

  for (int r = 0; r < KNN; ++r) {
    u64 wa = cand[0], wb = cand[1];
    #pragma unroll
    for (int dlt = 1; dlt < 64; dlt <<= 1) {
      u64 oa = __shfl_xor(wa, dlt);
      u64 ob = __shfl_xor(wb, dlt);
      wa = oa < wa ? oa : wa;
      wb = ob < wb ? ob : wb;
    }
    if (lane == r) { mykey[0] = wa; mykey[1] = wb; }
    u64 w2q[2] = {wa, wb};
    #pragma unroll
    for (int q = 0; q < 2; ++q) {
      const u64 w = w2q[q];
      if (cand[q] == w) {              // this lane supplied the winner
        e0[q] = e1[q]; e1[q] = e2[q]; e2[q] = ~0ull; --rem[q];
        if (rem[q] == 0) {
          // rare: rebuild top-3 of this lane's keys strictly greater than w
          const u64 lim = w;
          u64 f0 = ~0ull, f1 = ~0ull, f2 = ~0ull;
          for (int j = 0; j < 128; ++j) {
            int n = j*64 + lane;
            const float4 p = base[n];
            float dot = __builtin_fmaf(qz[q], p.z, __builtin_fmaf(qy[q], p.y, __fmul_rn(qx[q], p.x)));
            float d2  = __builtin_fmaf(-2.0f, dot, __fadd_rn(qn[q], p.w));
            u64 key = ((u64)ord_f32(d2) << 32) | (u32)n;
            if (key > lim) {
              u64 a0 = key < f0 ? key : f0;
              u64 A0 = key < f0 ? f0  : key;
              u64 a1 = A0 < f1 ? A0   : f1;
              u64 A1 = A0 < f1 ? f1   : A0;
              u64 a2 = A1 < f2 ? A1   : f2;
              f0 = a0; f1 = a1; f2 = a2;
            }
          }
          e0[q] = f0; e1[q] = f1; e2[q] = f2;
          rem[q] = (f2 != ~0ull) ? 3 : ((f1 != ~0ull) ? 2 : ((f0 != ~0ull) ? 1 : 0));
        }
        cand[q] = e0[q];
      }
    }
  }

  #pragma unroll
  for (int q = 0; q < 2; ++q) {
    if (lane < KNN) {
      u32 n = (u32)mykey[q];
      int bm = b*M_ + q0 + q;
      idx_out[bm*KNN + lane] = (int)n;
      const float4 p = base[n];
      local_out[(bm*KNN + lane)*3 + 0] = qx[q] - p.x;
      local_out[(bm*KNN + lane)*3 + 1] = qy[q] - p.y;
      local_out[(bm*KNN + lane)*3 + 2] = qz[q] - p.z;
    }
  }
}

// ---------------------------------------------------------------------------
// BN1 stats over local (B*M*K rows x 3 ch)
// ---------------------------------------------------------------------------
__global__ __launch_bounds__(256) void bn1_stats_kernel(
    const float* __restrict__ local, float* __restrict__ p1)
{
  const int t = threadIdx.x;
  const int gid = blockIdx.x*256 + t;
  float s0=0,s1=0,s2=0,q0=0,q1=0,q2=0;
  for (int r = gid; r < B_*M_*KNN; r += 65536) {
    float a = local[r*3+0], b = local[r*3+1], c = local[r*3+2];
    s0 += a; s1 += b; s2 += c;
    q0 = fmaf(a,a,q0); q1 = fmaf(b,b,q1); q2 = fmaf(c,c,q2);
  }
  __shared__ float red[256][8];
  red[t][0]=s0; red[t][1]=s1; red[t][2]=s2; red[t][3]=0.f;
  red[t][4]=q0; red[t][5]=q1; red[t][6]=q2; red[t][7]=0.f;
  __syncthreads();
  for (int st = 128; st >= 1; st >>= 1) {
    if (t < st) {
      #pragma unroll
      for (int j = 0; j < 8; ++j) red[t][j] += red[t+st][j];
    }
    __syncthreads();
  }
  if (t < 8) p1[blockIdx.x*8 + t] = red[0][t];
}

__global__ __launch_bounds__(128) void bn1_fold_kernel(
    const float* __restrict__ p1, const float* __restrict__ g1, const float* __restrict__ be1,
    const float* __restrict__ w1, const float* __restrict__ b1, float* __restrict__ prm)
{
  __shared__ float sc[3], sh[3];
  const int t = threadIdx.x;
  if (t < 3) {
    double s = 0, q = 0;
    for (int blk = 0; blk < 256; ++blk) { s += p1[blk*8+t]; q += p1[blk*8+4+t]; }
    double n = (double)(B_*M_*KNN);
    double m = s/n, v = q/n - m*m;
    double rs = 1.0/sqrt(v + 1e-5);
    float scale = (float)((double)g1[t]*rs);
    sc[t] = scale; sh[t] = be1[t] - (float)m*scale;
  }
  __syncthreads();
  if (t < 96) prm[t] = w1[t]*sc[t/32];
  if (t < 32) {
    float a = b1[t];
    for (int c = 0; c < 3; ++c) a = fmaf(sh[c], w1[c*32+t], a);
    prm[96+t] = a;
  }
}

// ---------------------------------------------------------------------------
// h1 stats (recomputes h1 = relu(local @ w1f + b1f)), 32 ch
// ---------------------------------------------------------------------------
__global__ __launch_bounds__(256) void h1_stats_kernel(
    const float* __restrict__ local, const float* __restrict__ prm, float* __restrict__ p2)
{
  const int t = threadIdx.x;
  const int k4 = (t & 7) * 4;
  float w0[4], w1q[4], w2q[4], b1q[4];
  #pragma unroll
  for (int i = 0; i < 4; ++i) {
    w0[i]  = prm[ 0 + k4 + i];
    w1q[i] = prm[32 + k4 + i];
    w2q[i] = prm[64 + k4 + i];
    b1q[i] = prm[96 + k4 + i];
  }
  float s[4] = {0,0,0,0}, sq[4] = {0,0,0,0};
  const int r0 = (blockIdx.x*256 + t) >> 3;
  for (int r = r0; r < B_*M_*KNN; r += 16384) {
    float l0 = local[r*3+0], l1 = local[r*3+1], l2 = local[r*3+2];
    #pragma unroll
    for (int i = 0; i < 4; ++i) {
      float v = fmaf(l2, w2q[i], fmaf(l1, w1q[i], fmaf(l0, w0[i], b1q[i])));
      v = fmaxf(v, 0.0f);
      s[i] += v; sq[i] = fmaf(v, v, sq[i]);
    }
  }
  __shared__ float red[256][8];
  #pragma unroll
  for (int i = 0; i < 4; ++i) { red[t][i] = s[i]; red[t][4+i] = sq[i]; }
  __syncthreads();
  for (int st = 128; st >= 8; st >>= 1) {
    if (t < st) {
      #pragma unroll
      for (int j = 0; j < 8; ++j) red[t][j] += red[t+st][j];
    }
    __syncthreads();
  }
  if (t < 8) {
    #pragma unroll
    for (int i = 0; i < 4; ++i) {
      p2[blockIdx.x*64 +      t*4 + i] = red[t][i];
      p2[blockIdx.x*64 + 32 + t*4 + i] = red[t][4+i];
    }
  }
}

__global__ __launch_bounds__(64) void bn2_fold_kernel(
    const float* __restrict__ p2, const float* __restrict__ g2, const float* __restrict__ be2,
    const float* __restrict__ w2, const float* __restrict__ b2, float* __restrict__ prm)
{
  __shared__ float sc[32], sh[32];
  const int t = threadIdx.x;
  if (t < 32) {
    double s = 0, q = 0;
    for (int blk = 0; blk < 512; ++blk) { s += p2[blk*64+t]; q += p2[blk*64+32+t]; }
    double n = (double)(B_*M_*KNN);
    double m = s/n, v = q/n - m*m;
    double rs = 1.0/sqrt(v + 1e-5);
    float scale = (float)((double)g2[t]*rs);
    sc[t] = scale; sh[t] = be2[t] - (float)m*scale;
  }
  __syncthreads();
  {
    int j = t;
    float a = b2[j];
    for (int k = 0; k < 32; ++k) {
      float wv = w2[k*64 + j];
      prm[128 + j*32 + k] = wv * sc[k];
      a = fmaf(sh[k], wv, a);
    }
    prm[2176 + j] = a;
  }
}

// ---------------------------------------------------------------------------
// fused: h2 = relu(h1 @ w2ft + b2f) + maxpool(8) -> pooled[.,0:64]
//        AND feat_prev gather + maxpool(8)       -> pooled[.,64:128]
// ---------------------------------------------------------------------------
__global__ __launch_bounds__(256) void h2_prev_pool_kernel(
    const float* __restrict__ local, const float* __restrict__ prm,
    const float* __restrict__ feat_prev, const int* __restrict__ idx,
    float* __restrict__ pooled)
{
  const int t = threadIdx.x;
  const int row = blockIdx.x*256 + t;
  const int bm = row >> 5, s = row & 31, d = s >> 3;
  const float l0 = local[row*3+0], l1 = local[row*3+1], l2 = local[row*3+2];
  float h1v[32];
  #pragma unroll
  for (int k = 0; k < 32; ++k) {
    float v = fmaf(l2, prm[64+k], fmaf(l1, prm[32+k], fmaf(l0, prm[0+k], prm[96+k])));
    h1v[k] = fmaxf(v, 0.0f);
  }
  const float* __restrict__ w2t = prm + 128;
  const float* __restrict__ b2f = prm + 2176;
  #pragma unroll 4
  for (int j = 0; j < 64; ++j) {
    float acc = b2f[j];
    #pragma unroll
    for (int k = 0; k < 32; ++k) acc = fmaf(h1v[k], w2t[j*32+k], acc);
    acc = fmaxf(acc, 0.0f);
    acc = fmaxf(acc, __shfl_xor(acc, 1));
    acc = fmaxf(acc, __shfl_xor(acc, 2));
    acc = fmaxf(acc, __shfl_xor(acc, 4));
    if ((s & 7) == 0) pooled[(bm*4 + d)*128 + j] = acc;
  }
  const int bm0 = blockIdx.x * 8;
  #pragma unroll
  for (int it = 0; it < 8; ++it) {
    const int task = it*256 + t;
    const int bmL  = task >> 8;
    const int dd   = (task >> 6) & 3;
    const int ch   = task & 63;
    const int bmg  = bm0 + bmL;
    const int bb   = bmg >> 11;
    float pm = -3.402823466e+38f;
    #pragma unroll
    for (int s8 = 0; s8 < 8; ++s8) {
      int n = idx[bmg*KNN + dd*8 + s8];
      float v = feat_prev[((size_t)(bb*N_ + n))*64 + ch];
      pm = fmaxf(pm, v);
    }
    pooled[(size_t)(bmg*4 + dd)*128 + 64 + ch] = pm;
  }
}

// ---------------------------------------------------------------------------
// BN3 stats over pooled (B*M*4 rows x 128 ch)
// ---------------------------------------------------------------------------
__global__ __launch_bounds__(256) void bn3_stats_kernel(
    const float* __restrict__ pooled, float* __restrict__ p3)
{
  const int t = threadIdx.x, c = t & 127, rr = t >> 7;
  float s = 0, q = 0;
  for (int r = blockIdx.x*2 + rr; r < B_*M_*DIV_; r += 512) {
    float v = pooled[(size_t)r*128 + c];
    s += v; q = fmaf(v, v, q);
  }
  __shared__ float red[256][2];
  red[t][0] = s; red[t][1] = q;
  __syncthreads();
  if (t < 128) {
    p3[blockIdx.x*256 +       t] = red[t][0] + red[t+128][0];
    p3[blockIdx.x*256 + 128 + t] = red[t][1] + red[t+128][1];
  }
}

__global__ __launch_bounds__(256) void bn3_fold_kernel(
    const float* __restrict__ p3, const float* __restrict__ g3, const float* __restrict__ be3,
    const float* __restrict__ wc, const float* __restrict__ bc, float* __restrict__ prm)
{
  __shared__ float sc[128], sh[128];
  const int t = threadIdx.x;
  if (t < 128) {
    double s = 0, q = 0;
    for (int blk = 0; blk < 256; ++blk) { s += p3[blk*256+t]; q += p3[blk*256+128+t]; }
    double n = (double)(B_*M_*DIV_);
    double m = s/n, v = q/n - m*m;
    double rs = 1.0/sqrt(v + 1e-5);
    float scale = (float)((double)g3[t]*rs);
    sc[t] = scale; sh[t] = be3[t] - (float)m*scale;
  }
  __syncthreads();
  for (int e = t; e < 512*128; e += 256) {
    int i = e >> 7, o = e & 127, dd = i >> 7, cc = i & 127;
    prm[2240 + e] = wc[o*512 + cc*4 + dd] * sc[cc];
  }
  if (t < 128) {
    int o = t;
    float a = bc[o];
    for (int cc = 0; cc < 128; ++cc) {
      float hsum = 0;
      #pragma unroll
      for (int dd = 0; dd < 4; ++dd) hsum += wc[o*512 + cc*4 + dd];
      a = fmaf(sh[cc], hsum, a);
    }
    prm[67776 + o] = a;
  }
}

// ---------------------------------------------------------------------------
// out = relu(pooled(16384x512) @ wcf_t(512x128) + bcf) ; fp32 tiled GEMM
// tile 32x128, 512 blocks, thread tile 2x8
// ---------------------------------------------------------------------------
__global__ __launch_bounds__(256) void conv_gemm_kernel(
    const float* __restrict__ pooled, const float* __restrict__ prm,
    float* __restrict__ outp)
{
  const float* __restrict__ Bw  = prm + 2240;    // [512][128]
  const float* __restrict__ bcf = prm + 67776;   // [128]
  __shared__ float As[32][36];
  __shared__ float Bs[32][128];
  const int t = threadIdx.x;
  const int cg_ = t & 15, rg = t >> 4;
  const int rowbase = blockIdx.x * 32;
  float acc[2][8];
  #pragma unroll
  for (int i = 0; i < 2; ++i)
    #pragma unroll
    for (int j = 0; j < 8; ++j) acc[i][j] = 0.f;

  float bb[8];
  #pragma unroll
  for (int j = 0; j < 8; ++j) bb[j] = bcf[cg_*8 + j];

  for (int k0 = 0; k0 < 512; k0 += 32) {
    {
      int r = t >> 3, qd = t & 7;
      const float4 v = *(const float4*)&pooled[(size_t)(rowbase+r)*512 + k0 + qd*4];
      As[qd*4+0][r] = v.x; As[qd*4+1][r] = v.y; As[qd*4+2][r] = v.z; As[qd*4+3][r] = v.w;
    }
    #pragma unroll
    for (int i = 0; i < 4; ++i) {
      int li = t + i*256;
      int kk = li >> 5, c4 = (li & 31) * 4;
      *(float4*)&Bs[kk][c4] = *(const float4*)&Bw[(size_t)(k0+kk)*128 + c4];
    }
    __syncthreads();
    #pragma unroll 8
    for (int kk = 0; kk < 32; ++kk) {
      float a0 = As[kk][rg*2], a1 = As[kk][rg*2+1];
      float4 b0 = *(const float4*)&Bs[kk][cg_*8];
      float4 b1 = *(const float4*)&Bs[kk][cg_*8+4];
      float bv[8] = {b0.x, b0.y, b0.z, b0.w, b1.x, b1.y, b1.z, b1.w};
      #pragma unroll
      for (int j = 0; j < 8; ++j) {
        acc[0][j] = fmaf(a0, bv[j], acc[0][j]);
        acc[1][j] = fmaf(a1, bv[j], acc[1][j]);
      }
    }
    __syncthreads();
  }
  #pragma unroll
  for (int i = 0; i < 2; ++i) {
    int r = rowbase + rg*2 + i;
    float4 o0, o1;
    o0.x = fmaxf(acc[i][0] + bb[0], 0.f);
    o0.y = fmaxf(acc[i][1] + bb[1], 0.f);
    o0.z = fmaxf(acc[i][2] + bb[2], 0.f);
    o0.w = fmaxf(acc[i][3] + bb[3], 0.f);
    o1.x = fmaxf(acc[i][4] + bb[4], 0.f);
    o1.y = fmaxf(acc[i][5] + bb[5], 0.f);
    o1.z = fmaxf(acc[i][6] + bb[6], 0.f);
    o1.w = fmaxf(acc[i][7] + bb[7], 0.f);
    *(float4*)&outp[(size_t)r*128 + cg_*8    ] = o0;
    *(float4*)&outp[(size_t)r*128 + cg_*8 + 4] = o1;
  }
}

// ---------------------------------------------------------------------------
extern "C" void kernel_launch(void* const* d_in, const int* in_sizes, int n_in,
                              void* d_out, int out_size, void* d_ws, size_t ws_size,
                              hipStream_t stream)
{
  (void)in_sizes; (void)n_in; (void)out_size; (void)ws_size;
  const float* points    = (const float*)d_in[0];
  const float* queries   = (const float*)d_in[1];
  const float* feat_prev = (const float*)d_in[2];
  const float* w1  = (const float*)d_in[3];
  const float* b1  = (const float*)d_in[4];
  const float* w2  = (const float*)d_in[5];
  const float* b2  = (const float*)d_in[6];
  const float* g1  = (const float*)d_in[7];
  const float* be1 = (const float*)d_in[8];
  const float* g2  = (const float*)d_in[9];
  const float* be2 = (const float*)d_in[10];
  const float* g3  = (const float*)d_in[11];
  const float* be3 = (const float*)d_in[12];
  const float* wc  = (const float*)d_in[13];
  const float* bc  = (const float*)d_in[14];
  float* outp = (float*)d_out;

  char* ws = (char*)d_ws;
  int*   idx    = (int*)ws;                          // 2MB
  float* local  = (float*)(ws + (2u<<20));           // 6MB  -> ends 8MB
  float* pooled = (float*)(ws + (8u<<20));           // 32MB -> ends 40MB
  float* prm    = (float*)(ws + (40u<<20));          // ~275KB
  float* p1     = (float*)(ws + (41u<<20));          // 2048 f
  float* p2     = p1 + 8192;                         // 32768 f
  float4* ppk   = (float4*)(ws + (42u<<20));         // 1MB
  float* p3     = (float*)(ws + (43u<<20));          // 65536 f

  pack_kernel    <<<256,   256, 0, stream>>>(points, ppk);
  knn_kernel     <<<2048,  256, 0, stream>>>(ppk, queries, idx, local);
  bn1_stats_kernel<<<256,  256, 0, stream>>>(local, p1);
  bn1_fold_kernel<<<1,     128, 0, stream>>>(p1, g1, be1, w1, b1, prm);
  h1_stats_kernel<<<512,   256, 0, stream>>>(local, prm, p2);
  bn2_fold_kernel<<<1,      64, 0, stream>>>(p2, g2, be2, w2, b2, prm);
  h2_prev_pool_kernel<<<2048, 256, 0, stream>>>(local, prm, feat_prev, idx, pooled);
  bn3_stats_kernel<<<256,  256, 0, stream>>>(pooled, p3);
  bn3_fold_kernel<<<1,     256, 0, stream>>>(p3, g3, be3, wc, bc, prm);
  conv_gemm_kernel<<<512,  256, 0, stream>>>(pooled, prm, outp);
}